// Round 7
// baseline (1137.516 us; speedup 1.0000x reference)
//
#include <hip/hip_runtime.h>

typedef unsigned short u16;
typedef __attribute__((ext_vector_type(4))) unsigned short us4;
typedef __attribute__((ext_vector_type(4))) float f4;
typedef __attribute__((ext_vector_type(8))) short bf16x8;
typedef __attribute__((ext_vector_type(4))) float f32x4;

__device__ __forceinline__ u16 f2bf(float x) {
  unsigned u = __float_as_uint(x);
  return (u16)((u + 0x7FFFu + ((u >> 16) & 1u)) >> 16);
}
__device__ __forceinline__ float sigm(float x) { return 1.f / (1.f + __expf(-x)); }
__device__ __forceinline__ float tanhf_(float x) { return 2.f / (1.f + __expf(-2.f * x)) - 1.f; }

// ---------------------------------------------------------------------------
// Setup kernel 1: convert W/U fp32 -> bf16, gate-major.
// ---------------------------------------------------------------------------
__global__ void convert_wu_kernel(const float* __restrict__ w0, const float* __restrict__ w1,
                                  const float* __restrict__ w2, const float* __restrict__ w3,
                                  const float* __restrict__ u0, const float* __restrict__ u1,
                                  const float* __restrict__ u2, const float* __restrict__ u3,
                                  u16* __restrict__ Wb, u16* __restrict__ Ub) {
  int mat = blockIdx.x >> 10;
  int off4 = (int)(blockIdx.x & 1023) * 256 + threadIdx.x;
  const float* src; u16* dst;
  switch (mat) {
    case 0: src = w0; dst = Wb; break;
    case 1: src = w1; dst = Wb + 1048576; break;
    case 2: src = w2; dst = Wb + 2097152; break;
    case 3: src = w3; dst = Wb + 3145728; break;
    case 4: src = u0; dst = Ub; break;
    case 5: src = u1; dst = Ub + 1048576; break;
    case 6: src = u2; dst = Ub + 2097152; break;
    default: src = u3; dst = Ub + 3145728; break;
  }
  f4 v = ((const f4*)src)[off4];
  us4 o = {f2bf(v[0]), f2bf(v[1]), f2bf(v[2]), f2bf(v[3])};
  ((us4*)dst)[off4] = o;
}

// ---------------------------------------------------------------------------
// Setup kernel 2: Xleaf[n][k] = bf16(tokens[leaf_ids[n]][k]).
// ---------------------------------------------------------------------------
__global__ void gather_leaf_kernel(const float* __restrict__ tokens,
                                   const int* __restrict__ ids, u16* __restrict__ Xl) {
  int n = blockIdx.x, t = threadIdx.x;
  int tok = ids[n];
  f4 v = ((const f4*)(tokens + (size_t)tok * 1024))[t];
  us4 o = {f2bf(v[0]), f2bf(v[1]), f2bf(v[2]), f2bf(v[3])};
  ((us4*)(Xl + (size_t)n * 1024))[t] = o;
}

// ---------------------------------------------------------------------------
// Setup kernel 3 (fp32 dots, tiny): xw[op][g][j], leafC[5][j].
// ---------------------------------------------------------------------------
__global__ void precompute_kernel(const float* __restrict__ op_emb,
    const float* __restrict__ w0, const float* __restrict__ w1,
    const float* __restrict__ w2, const float* __restrict__ w3,
    const float* __restrict__ u0, const float* __restrict__ u1,
    const float* __restrict__ u2, const float* __restrict__ u3,
    const float* __restrict__ b0, const float* __restrict__ b1,
    const float* __restrict__ b2, const float* __restrict__ b3,
    const float* __restrict__ h_init,
    float* __restrict__ xw, float* __restrict__ leafC) {
  int id = blockIdx.x * 256 + threadIdx.x;
  if (id < 16384) {
    int op = id >> 12, g = (id >> 10) & 3, j = id & 1023;
    const float* wsrc; const float* bs;
    switch (g) {
      case 0: wsrc = w0; bs = b0; break;
      case 1: wsrc = w1; bs = b1; break;
      case 2: wsrc = w2; bs = b2; break;
      default: wsrc = w3; bs = b3; break;
    }
    const f4* xr = (const f4*)(op_emb + (size_t)op * 1024);
    const f4* wr = (const f4*)(wsrc + (size_t)j * 1024);
    float s = bs[j];
    for (int k = 0; k < 256; ++k) {
      f4 a = xr[k], b = wr[k];
      s += a[0] * b[0] + a[1] * b[1] + a[2] * b[2] + a[3] * b[3];
    }
    xw[id] = s;
  } else if (id < 21504) {
    int id2 = id - 16384;
    int sel = id2 >> 10, j = id2 & 1023;
    const f4* h0 = (const f4*)h_init;
    const f4* h1 = (const f4*)(h_init + 1024);
    float s;
    if (sel < 3) {
      const float* usrc; const float* bs;
      switch (sel) {
        case 0: usrc = u0; bs = b0; break;
        case 1: usrc = u1; bs = b1; break;
        default: usrc = u2; bs = b2; break;
      }
      const f4* wr = (const f4*)(usrc + (size_t)j * 1024);
      s = bs[j];
      for (int k = 0; k < 256; ++k) {
        f4 a0 = h0[k], a1 = h1[k], b = wr[k];
        s += (a0[0] + a1[0]) * b[0] + (a0[1] + a1[1]) * b[1] +
             (a0[2] + a1[2]) * b[2] + (a0[3] + a1[3]) * b[3];
      }
    } else {
      const f4* hs = (sel == 3) ? h0 : h1;
      const f4* wr = (const f4*)(u3 + (size_t)j * 1024);
      s = b3[j];
      for (int k = 0; k < 256; ++k) {
        f4 a = hs[k], b = wr[k];
        s += a[0] * b[0] + a[1] * b[1] + a[2] * b[2] + a[3] * b[3];
      }
    }
    leafC[id2] = s;
  }
}

// ---------------------------------------------------------------------------
// Main fused GEMM + TreeLSTM node kernel, round 7:
// WAVE-AUTONOMOUS, ZERO-LDS, ZERO-BARRIER.
// Waves partition ROWS (not gates): wave w owns rows [r0+w*NW*16, +NW*16),
// computing ALL 4 gates over a 16-col stripe. acc[t][g] = f32x4.
// A and B fragments are direct global->VGPR 16B contiguous loads,
// double-buffered; loads for iter i+1 are issued BEFORE the MFMAs of iter i,
// so consumption waits on loads ~1 full iteration (~220 cyc) old. No LDS, no
// __syncthreads anywhere -> no block-coupled stalls.
// Epilogue is register-only: one lane holds all 4 gates of (row,col), and
// child rows 2p/2p+1 are adjacent acc regs (C/D row = quad*4+k), so the
// child-sum pairing is in-lane. Stores coalesce in 64B (fp32) segments.
// Grid: 1D, stripe = blockIdx & 63 (16 cols each), rowblk = blockIdx >> 6.
// ---------------------------------------------------------------------------
template <int NW>   // row-fragments per wave (4 -> 256-row block, 1 -> 64)
__global__ __launch_bounds__(256, (NW == 4 ? 2 : 3)) void tree_gemm(
    const u16* __restrict__ A, const u16* __restrict__ Wm,
    const float* __restrict__ consts,   // leafC[5][1024] or xw[4][4][1024]
    const int* __restrict__ ops,        // nullptr for leaf
    const float* __restrict__ c_in,     // c_init[2][1024] or child c
    float* __restrict__ c_out, u16* __restrict__ h_out,
    int nrows, int m_parents, int is_leaf, float* __restrict__ out_root) {
  constexpr int WR = NW * 16;      // rows per wave
  constexpr int BR = 4 * WR;       // rows per block

  const int tid = threadIdx.x;
  const int wave = tid >> 6;
  const int lane = tid & 63;
  const int ln15 = lane & 15, quad = lane >> 4;
  const int stripe = blockIdx.x & 63;
  const int rowblk = blockIdx.x >> 6;
  const int r0 = rowblk * BR;
  const int j0 = stripe * 16;
  const int wrow0 = r0 + wave * WR;

  // ---- fragment pointers (16B contiguous per lane) ------------------------
  const char* pA[NW];
#pragma unroll
  for (int t = 0; t < NW; ++t) {
    int row = wrow0 + t * 16 + ln15;
    if (row >= nrows) row = nrows - 1;
    pA[t] = (const char*)A + (size_t)row * 2048 + quad * 16;
  }
  const char* pB[4];
#pragma unroll
  for (int g = 0; g < 4; ++g)
    pB[g] = (const char*)Wm + (size_t)(g * 1024 + j0 + ln15) * 2048 + quad * 16;

  f32x4 acc[NW][4];
#pragma unroll
  for (int t = 0; t < NW; ++t)
#pragma unroll
    for (int g = 0; g < 4; ++g) acc[t][g] = (f32x4){0.f, 0.f, 0.f, 0.f};

  // ---- K-loop: 16 iters of BK=64 (2 MFMA k-steps), 2-deep reg buffers -----
  bf16x8 Ab[2][NW][2], Bb[2][4][2];
#pragma unroll
  for (int t = 0; t < NW; ++t)
#pragma unroll
    for (int ks = 0; ks < 2; ++ks)
      Ab[0][t][ks] = *(const bf16x8*)(pA[t] + ks * 64);
#pragma unroll
  for (int g = 0; g < 4; ++g)
#pragma unroll
    for (int ks = 0; ks < 2; ++ks)
      Bb[0][g][ks] = *(const bf16x8*)(pB[g] + ks * 64);

#pragma unroll
  for (int it = 0; it < 16; ++it) {
    const int cur = it & 1, nxt = cur ^ 1;
    if (it < 15) {
      const int off = (it + 1) * 128;   // imm-foldable (max 1984+64)
#pragma unroll
      for (int t = 0; t < NW; ++t)
#pragma unroll
        for (int ks = 0; ks < 2; ++ks)
          Ab[nxt][t][ks] = *(const bf16x8*)(pA[t] + off + ks * 64);
#pragma unroll
      for (int g = 0; g < 4; ++g)
#pragma unroll
        for (int ks = 0; ks < 2; ++ks)
          Bb[nxt][g][ks] = *(const bf16x8*)(pB[g] + off + ks * 64);
    }
#pragma unroll
    for (int ks = 0; ks < 2; ++ks)
#pragma unroll
      for (int g = 0; g < 4; ++g)
#pragma unroll
        for (int t = 0; t < NW; ++t)
          acc[t][g] = __builtin_amdgcn_mfma_f32_16x16x32_bf16(
              Ab[cur][t][ks], Bb[cur][g][ks], acc[t][g], 0, 0, 0);
  }

  // ---- register-only epilogue --------------------------------------------
  const int col = j0 + ln15;

  if (is_leaf) {
    const float ci0 = c_in[col], ci1 = c_in[1024 + col];
    const float k0 = consts[col], k1 = consts[1024 + col], k2 = consts[2048 + col];
    const float k3 = consts[3072 + col], k4 = consts[4096 + col];
#pragma unroll
    for (int t = 0; t < NW; ++t)
#pragma unroll
      for (int k = 0; k < 4; ++k) {
        int n = wrow0 + t * 16 + quad * 4 + k;
        if (n < nrows) {
          float i_ = sigm(acc[t][0][k] + k0);
          float o_ = sigm(acc[t][1][k] + k1);
          float u_ = tanhf_(acc[t][2][k] + k2);
          float f0 = sigm(acc[t][3][k] + k3);
          float f1 = sigm(acc[t][3][k] + k4);
          float c = i_ * u_ + f0 * ci0 + f1 * ci1;
          float h = o_ * tanhf_(c);
          c_out[(size_t)n * 1024 + col] = c;
          h_out[(size_t)n * 1024 + col] = f2bf(h);
        }
      }
  } else {
#pragma unroll
    for (int t = 0; t < NW; ++t)
#pragma unroll
      for (int kp = 0; kp < 2; ++kp) {
        int np = (wrow0 >> 1) + t * 8 + quad * 2 + kp;
        if (np < m_parents) {
          int ka = 2 * kp, kb = 2 * kp + 1;
          int op = ops[np];
          const float* xwop = consts + ((unsigned)op << 12);
          float cia = c_in[(size_t)(2 * np) * 1024 + col];
          float cib = c_in[(size_t)(2 * np + 1) * 1024 + col];
          float i_ = sigm(acc[t][0][ka] + acc[t][0][kb] + xwop[col]);
          float o_ = sigm(acc[t][1][ka] + acc[t][1][kb] + xwop[1024 + col]);
          float u_ = tanhf_(acc[t][2][ka] + acc[t][2][kb] + xwop[2048 + col]);
          float f0 = sigm(acc[t][3][ka] + xwop[3072 + col]);
          float f1 = sigm(acc[t][3][kb] + xwop[3072 + col]);
          float c = i_ * u_ + f0 * cia + f1 * cib;
          float h = o_ * tanhf_(c);
          if (m_parents == 1) {
            out_root[col] = c;
            out_root[1024 + col] = h;
          } else {
            c_out[(size_t)np * 1024 + col] = c;
            h_out[(size_t)np * 1024 + col] = f2bf(h);
          }
        }
      }
  }
}

// ---------------------------------------------------------------------------
extern "C" void kernel_launch(void* const* d_in, const int* in_sizes, int n_in,
                              void* d_out, int out_size, void* d_ws, size_t ws_size,
                              hipStream_t stream) {
  const float* tokens = (const float*)d_in[0];
  const int* leaf_ids = (const int*)d_in[1];
  const int* op_ids = (const int*)d_in[2];
  const float* W0 = (const float*)d_in[3];
  const float* W1 = (const float*)d_in[4];
  const float* W2 = (const float*)d_in[5];
  const float* W3 = (const float*)d_in[6];
  const float* U0 = (const float*)d_in[7];
  const float* U1 = (const float*)d_in[8];
  const float* U2 = (const float*)d_in[9];
  const float* U3 = (const float*)d_in[10];
  const float* B0 = (const float*)d_in[11];
  const float* B1 = (const float*)d_in[12];
  const float* B2 = (const float*)d_in[13];
  const float* B3 = (const float*)d_in[14];
  const float* op_emb = (const float*)d_in[15];
  const float* c_init = (const float*)d_in[16];
  const float* h_init = (const float*)d_in[17];
  float* out = (float*)d_out;

  char* ws = (char*)d_ws;
  u16* Wb = (u16*)ws;
  u16* Ub = Wb + (size_t)4 * 1024 * 1024;
  u16* Xl = Ub + (size_t)4 * 1024 * 1024;
  u16* hA = Xl + (size_t)8192 * 1024;
  u16* hB = hA + (size_t)8192 * 1024;
  float* cA = (float*)(hB + (size_t)4096 * 1024);
  float* cB = cA + (size_t)8192 * 1024;
  float* xw = cB + (size_t)4096 * 1024;
  float* lc = xw + 16 * 1024;

  convert_wu_kernel<<<8192, 256, 0, stream>>>(W0, W1, W2, W3, U0, U1, U2, U3, Wb, Ub);
  gather_leaf_kernel<<<8192, 256, 0, stream>>>(tokens, leaf_ids, Xl);
  precompute_kernel<<<84, 256, 0, stream>>>(op_emb, W0, W1, W2, W3, U0, U1, U2, U3,
                                            B0, B1, B2, B3, h_init, xw, lc);

  // leaves: 8192 rows -> NW=4 (256-row blocks): 32 rowgroups x 64 stripes
  tree_gemm<4><<<32 * 64, 256, 0, stream>>>(Xl, Wb, lc, nullptr, c_init,
                                            cA, hA, 8192, 0, 1, out);

  const u16* hin = hA; const float* cin = cA;
  u16* hout = hB; float* cout = cB;
  for (int l = 12; l >= 0; --l) {
    int m = 1 << l;
    int nrows = 2 * m;
    if (nrows >= 256) {
      tree_gemm<4><<<(nrows / 256) * 64, 256, 0, stream>>>(
          hin, Ub, xw, op_ids + (m - 1), cin, cout, hout, nrows, m, 0, out);
    } else {
      tree_gemm<1><<<((nrows + 63) / 64) * 64, 256, 0, stream>>>(
          hin, Ub, xw, op_ids + (m - 1), cin, cout, hout, nrows, m, 0, out);
    }
    const u16* th = hin; hin = hout; hout = (u16*)th;
    const float* tc = cin; cin = cout; cout = (float*)tc;
  }
}

// Round 8
// 805.210 us; speedup vs baseline: 1.4127x; 1.4127x over previous
//
#include <hip/hip_runtime.h>

typedef unsigned short u16;
typedef __attribute__((ext_vector_type(4))) unsigned short us4;
typedef __attribute__((ext_vector_type(4))) float f4;
typedef __attribute__((ext_vector_type(8))) short bf16x8;
typedef __attribute__((ext_vector_type(4))) float f32x4;

__device__ __forceinline__ u16 f2bf(float x) {
  unsigned u = __float_as_uint(x);
  return (u16)((u + 0x7FFFu + ((u >> 16) & 1u)) >> 16);
}
__device__ __forceinline__ float b2f(u16 s) {
  return __uint_as_float(((unsigned)s) << 16);
}
__device__ __forceinline__ float sigm(float x) { return 1.f / (1.f + __expf(-x)); }
__device__ __forceinline__ float tanhf_(float x) { return 2.f / (1.f + __expf(-2.f * x)) - 1.f; }

// ---------------------------------------------------------------------------
// Setup kernel 1: convert W/U fp32 -> bf16 in FRAGMENT-MAJOR layout:
//   B'[g][kc][c][lane][j]  (u16 idx = g*1048576 + kc*32768 + c*512 + lane*8 + j)
// where the MFMA B-fragment for (gate g, col-frag c, k-granule kc) read by
// lane l is B[col = c*16 + (l&15)][k = kc*32 + (l>>4)*8 + j], j=0..7.
// A wave's fragment load is then 64 lanes x contiguous 16B = 1KB coalesced.
// grid 4096 x 256 (1,048,576 threads; 8 elems each; W set + U set).
// ---------------------------------------------------------------------------
__global__ void convert_frag_kernel(const float* __restrict__ w0, const float* __restrict__ w1,
                                    const float* __restrict__ w2, const float* __restrict__ w3,
                                    const float* __restrict__ u0, const float* __restrict__ u1,
                                    const float* __restrict__ u2, const float* __restrict__ u3,
                                    u16* __restrict__ Wb, u16* __restrict__ Ub) {
  unsigned id = blockIdx.x * 256 + threadIdx.x;
  unsigned mset = id >> 19;
  unsigned r = id & 0x7FFFFu;
  unsigned g = r >> 17, kc = (r >> 12) & 31, c = (r >> 6) & 63, l = r & 63;
  const float* src;
  if (mset == 0) {
    switch (g) { case 0: src = w0; break; case 1: src = w1; break;
                 case 2: src = w2; break; default: src = w3; break; }
  } else {
    switch (g) { case 0: src = u0; break; case 1: src = u1; break;
                 case 2: src = u2; break; default: src = u3; break; }
  }
  unsigned col = c * 16 + (l & 15);
  unsigned k0 = kc * 32 + (l >> 4) * 8;
  const f4* s = (const f4*)(src + (size_t)col * 1024 + k0);
  f4 v0 = s[0], v1 = s[1];
  u16* dst = (mset ? Ub : Wb) + (size_t)g * 1048576 + kc * 32768 + c * 512 + l * 8;
  us4 o0 = {f2bf(v0[0]), f2bf(v0[1]), f2bf(v0[2]), f2bf(v0[3])};
  us4 o1 = {f2bf(v1[0]), f2bf(v1[1]), f2bf(v1[2]), f2bf(v1[3])};
  ((us4*)dst)[0] = o0;
  ((us4*)dst)[1] = o1;
}

// ---------------------------------------------------------------------------
// Setup kernel 2: Xleaf[n][k] = bf16(tokens[leaf_ids[n]][k]).  (row-major)
// ---------------------------------------------------------------------------
__global__ void gather_leaf_kernel(const float* __restrict__ tokens,
                                   const int* __restrict__ ids, u16* __restrict__ Xl) {
  int n = blockIdx.x, t = threadIdx.x;
  int tok = ids[n];
  f4 v = ((const f4*)(tokens + (size_t)tok * 1024))[t];
  us4 o = {f2bf(v[0]), f2bf(v[1]), f2bf(v[2]), f2bf(v[3])};
  ((us4*)(Xl + (size_t)n * 1024))[t] = o;
}

// ---------------------------------------------------------------------------
// Setup kernel 3 (fp32 dots, tiny): xw[op][g][j], leafC[5][j].
// ---------------------------------------------------------------------------
__global__ void precompute_kernel(const float* __restrict__ op_emb,
    const float* __restrict__ w0, const float* __restrict__ w1,
    const float* __restrict__ w2, const float* __restrict__ w3,
    const float* __restrict__ u0, const float* __restrict__ u1,
    const float* __restrict__ u2, const float* __restrict__ u3,
    const float* __restrict__ b0, const float* __restrict__ b1,
    const float* __restrict__ b2, const float* __restrict__ b3,
    const float* __restrict__ h_init,
    float* __restrict__ xw, float* __restrict__ leafC) {
  int id = blockIdx.x * 256 + threadIdx.x;
  if (id < 16384) {
    int op = id >> 12, g = (id >> 10) & 3, j = id & 1023;
    const float* wsrc; const float* bs;
    switch (g) {
      case 0: wsrc = w0; bs = b0; break;
      case 1: wsrc = w1; bs = b1; break;
      case 2: wsrc = w2; bs = b2; break;
      default: wsrc = w3; bs = b3; break;
    }
    const f4* xr = (const f4*)(op_emb + (size_t)op * 1024);
    const f4* wr = (const f4*)(wsrc + (size_t)j * 1024);
    float s = bs[j];
    for (int k = 0; k < 256; ++k) {
      f4 a = xr[k], b = wr[k];
      s += a[0] * b[0] + a[1] * b[1] + a[2] * b[2] + a[3] * b[3];
    }
    xw[id] = s;
  } else if (id < 21504) {
    int id2 = id - 16384;
    int sel = id2 >> 10, j = id2 & 1023;
    const f4* h0 = (const f4*)h_init;
    const f4* h1 = (const f4*)(h_init + 1024);
    float s;
    if (sel < 3) {
      const float* usrc; const float* bs;
      switch (sel) {
        case 0: usrc = u0; bs = b0; break;
        case 1: usrc = u1; bs = b1; break;
        default: usrc = u2; bs = b2; break;
      }
      const f4* wr = (const f4*)(usrc + (size_t)j * 1024);
      s = bs[j];
      for (int k = 0; k < 256; ++k) {
        f4 a0 = h0[k], a1 = h1[k], b = wr[k];
        s += (a0[0] + a1[0]) * b[0] + (a0[1] + a1[1]) * b[1] +
             (a0[2] + a1[2]) * b[2] + (a0[3] + a1[3]) * b[3];
      }
    } else {
      const f4* hs = (sel == 3) ? h0 : h1;
      const f4* wr = (const f4*)(u3 + (size_t)j * 1024);
      s = b3[j];
      for (int k = 0; k < 256; ++k) {
        f4 a = hs[k], b = wr[k];
        s += a[0] * b[0] + a[1] * b[1] + a[2] * b[2] + a[3] * b[3];
      }
    }
    leafC[id2] = s;
  }
}

// ---------------------------------------------------------------------------
// Main fused GEMM + TreeLSTM node kernel, round 8.
// Block tile: 128 rows x 64 cols x 4 gates. Waves partition (row-half x
// gate-pair): wave = (pair = w>>1 -> rows [pair*64, +64)) x (gp = (w&1)*2 ->
// gates {gp, gp+1}) x 64 cols. acc[4][2][4] f32x4 = 128 regs.
//   A: LDS-staged (global_load_lds w=16, XOR-granule swizzle - verified
//      r3-r6), double-buffered, ONE barrier per BK=64 chunk; each A byte
//      read by only 2 waves (vs 4 in r5).
//   B: fragment-major layout (see convert_frag_kernel) -> every B load is
//      64-lane-contiguous 1KB. Two register buffers (Bk0/Bk1), prefetched
//      ~half-chunk ahead; per-wave vmcnt dependency only.
//   Epilogue: waves 1,3 (gates u,f) write tiles to LDS (stride 68,
//      conflict-free); waves 0,2 (gates i,o in regs) finalize + store.
//      Child rows 2p/2p+1 are in-lane adjacent acc elements.
// Stripe pinning: stripe = blockIdx & 15 -> per-XCD B slice 1MB, L2-resident.
// ---------------------------------------------------------------------------
__global__ __launch_bounds__(256, 2) void tree_gemm(
    const u16* __restrict__ A, const u16* __restrict__ Bf,
    const float* __restrict__ consts,   // leafC[5][1024] or xw[4][4][1024]
    const int* __restrict__ ops,        // nullptr for leaf
    const float* __restrict__ c_in,     // c_init[2][1024] or child c
    float* __restrict__ c_out, u16* __restrict__ h_out,
    int nrows, int m_parents, int is_leaf, float* __restrict__ out_root) {
  // staging dbuf = 2 x 16KB = 32KB; epilogue tiles = 4*64*68 u16 = 34816B.
  __shared__ __align__(16) u16 smem[4 * 64 * 68];
  char* sc = (char*)smem;

  const int tid = threadIdx.x;
  const int wave = tid >> 6;
  const int lane = tid & 63;
  const int ln15 = lane & 15, quad = lane >> 4;
  const int sub = lane >> 3, gsel = lane & 7;
  const int stripe = blockIdx.x & 15;
  const int rowblk = blockIdx.x >> 4;
  const int r0 = rowblk * 128;
  const int j0 = stripe * 64;
  const int pair = wave >> 1;          // row half
  const int gp = (wave & 1) * 2;       // gate pair base

  // ---- A staging sources (16KB/chunk = 4 x 16B per thread) ----------------
  const char* pAsrc[4];
  unsigned a_dst[4];
#pragma unroll
  for (int i = 0; i < 4; ++i) {
    int slot = (wave * 4 + i) * 8 + sub;
    int row = r0 + slot; if (row >= nrows) row = nrows - 1;
    pAsrc[i] = (const char*)(A + (size_t)row * 1024 + (unsigned)((gsel ^ sub) * 8));
    a_dst[i] = (unsigned)((wave * 4 + i) * 1024 + lane * 16);
  }
  // ---- B fragment bases (frag-major: wave-uniform + lane*16) --------------
  const u16* pB[2][4];
#pragma unroll
  for (int gg = 0; gg < 2; ++gg)
#pragma unroll
    for (int cf = 0; cf < 4; ++cf)
      pB[gg][cf] = Bf + (size_t)(gp + gg) * 1048576 +
                   (unsigned)((stripe * 4 + cf) * 512) + (unsigned)(lane * 8);

  // ---- A LDS fragment read addresses (within one 16KB buffer) -------------
  unsigned a_rd[4][2];
#pragma unroll
  for (int t = 0; t < 4; ++t) {
    int slot = pair * 64 + t * 16 + ln15;
#pragma unroll
    for (int ks = 0; ks < 2; ++ks)
      a_rd[t][ks] = (unsigned)(slot * 128 + (((ks * 4 + quad) ^ (slot & 7)) * 16));
  }

  f32x4 acc[4][2][4];
#pragma unroll
  for (int t = 0; t < 4; ++t)
#pragma unroll
    for (int gg = 0; gg < 2; ++gg)
#pragma unroll
      for (int cf = 0; cf < 4; ++cf) acc[t][gg][cf] = (f32x4){0.f, 0.f, 0.f, 0.f};

#define STAGE_CHUNK(CH)                                                           \
  do {                                                                            \
    const unsigned _bb = (unsigned)(((CH) & 1) * 16384);                          \
    _Pragma("unroll") for (int _i = 0; _i < 4; ++_i)                              \
        __builtin_amdgcn_global_load_lds(                                         \
            (const __attribute__((address_space(1))) void*)(pAsrc[_i] + (CH) * 128), \
            (__attribute__((address_space(3))) void*)(sc + _bb + a_dst[_i]),      \
            16, 0, 0);                                                            \
  } while (0)

  // prologue: stage chunk 0; load B(kc=0) into Bk0
  STAGE_CHUNK(0);
  bf16x8 Bk0[2][4], Bk1[2][4];
#pragma unroll
  for (int gg = 0; gg < 2; ++gg)
#pragma unroll
    for (int cf = 0; cf < 4; ++cf)
      Bk0[gg][cf] = *(const bf16x8*)(pB[gg][cf]);

#pragma unroll
  for (int ch = 0; ch < 16; ++ch) {
    __syncthreads();  // drains stage(ch) (issued ~1 chunk ago)
    if (ch < 15) STAGE_CHUNK(ch + 1);
    // prefetch B for this chunk's ks1 (kc = 2ch+1)
#pragma unroll
    for (int gg = 0; gg < 2; ++gg)
#pragma unroll
      for (int cf = 0; cf < 4; ++cf)
        Bk1[gg][cf] = *(const bf16x8*)(pB[gg][cf] + (size_t)(2 * ch + 1) * 32768);
    const unsigned cb = (unsigned)((ch & 1) * 16384);
    // ks0
    {
      bf16x8 af[4];
#pragma unroll
      for (int t = 0; t < 4; ++t) af[t] = *(const bf16x8*)(sc + cb + a_rd[t][0]);
#pragma unroll
      for (int t = 0; t < 4; ++t)
#pragma unroll
        for (int gg = 0; gg < 2; ++gg)
#pragma unroll
          for (int cf = 0; cf < 4; ++cf)
            acc[t][gg][cf] = __builtin_amdgcn_mfma_f32_16x16x32_bf16(
                af[t], Bk0[gg][cf], acc[t][gg][cf], 0, 0, 0);
    }
    // prefetch B for next chunk's ks0 (kc = 2ch+2)
    if (ch < 15) {
#pragma unroll
      for (int gg = 0; gg < 2; ++gg)
#pragma unroll
        for (int cf = 0; cf < 4; ++cf)
          Bk0[gg][cf] = *(const bf16x8*)(pB[gg][cf] + (size_t)(2 * ch + 2) * 32768);
    }
    // ks1
    {
      bf16x8 af[4];
#pragma unroll
      for (int t = 0; t < 4; ++t) af[t] = *(const bf16x8*)(sc + cb + a_rd[t][1]);
#pragma unroll
      for (int t = 0; t < 4; ++t)
#pragma unroll
        for (int gg = 0; gg < 2; ++gg)
#pragma unroll
          for (int cf = 0; cf < 4; ++cf)
            acc[t][gg][cf] = __builtin_amdgcn_mfma_f32_16x16x32_bf16(
                af[t], Bk1[gg][cf], acc[t][gg][cf], 0, 0, 0);
    }
  }
#undef STAGE_CHUNK

  // ---- epilogue -----------------------------------------------------------
  __syncthreads();  // staging reads done before tile overwrite
  if (wave & 1) {
    // writer waves (gates u,f): tiles (pair*2+gg) of 64 rows x 68 stride
#pragma unroll
    for (int t = 0; t < 4; ++t)
#pragma unroll
      for (int gg = 0; gg < 2; ++gg)
#pragma unroll
        for (int cf = 0; cf < 4; ++cf)
#pragma unroll
          for (int k = 0; k < 4; ++k) {
            int r = t * 16 + quad * 4 + k;
            smem[((pair * 2 + gg) * 64 + r) * 68 + cf * 16 + ln15] =
                f2bf(acc[t][gg][cf][k]);
          }
  }
  __syncthreads();
  if (!(wave & 1)) {
    const int rbase = r0 + pair * 64;
    if (is_leaf) {
#pragma unroll
      for (int cf = 0; cf < 4; ++cf) {
        const int col = j0 + cf * 16 + ln15;
        const float k0c = consts[col], k1c = consts[1024 + col];
        const float k2c = consts[2048 + col], k3c = consts[3072 + col];
        const float k4c = consts[4096 + col];
        const float ci0 = c_in[col], ci1 = c_in[1024 + col];
#pragma unroll
        for (int t = 0; t < 4; ++t)
#pragma unroll
          for (int k = 0; k < 4; ++k) {
            int r = t * 16 + quad * 4 + k;
            int n = rbase + r;
            if (n < nrows) {
              float g2 = b2f(smem[((pair * 2 + 0) * 64 + r) * 68 + cf * 16 + ln15]);
              float g3 = b2f(smem[((pair * 2 + 1) * 64 + r) * 68 + cf * 16 + ln15]);
              float i_ = sigm(acc[t][0][cf][k] + k0c);
              float o_ = sigm(acc[t][1][cf][k] + k1c);
              float u_ = tanhf_(g2 + k2c);
              float f0 = sigm(g3 + k3c);
              float f1 = sigm(g3 + k4c);
              float c = i_ * u_ + f0 * ci0 + f1 * ci1;
              float h = o_ * tanhf_(c);
              c_out[(size_t)n * 1024 + col] = c;
              h_out[(size_t)n * 1024 + col] = f2bf(h);
            }
          }
      }
    } else {
#pragma unroll
      for (int cf = 0; cf < 4; ++cf) {
        const int col = j0 + cf * 16 + ln15;
#pragma unroll
        for (int t = 0; t < 4; ++t)
#pragma unroll
          for (int kp = 0; kp < 2; ++kp) {
            int np = (rbase >> 1) + t * 8 + quad * 2 + kp;
            if (np < m_parents) {
              int ra = t * 16 + quad * 4 + 2 * kp, rb = ra + 1;
              int op = ops[np];
              const float* xwop = consts + ((unsigned)op << 12);
              float g2a = b2f(smem[((pair * 2 + 0) * 64 + ra) * 68 + cf * 16 + ln15]);
              float g2b = b2f(smem[((pair * 2 + 0) * 64 + rb) * 68 + cf * 16 + ln15]);
              float g3a = b2f(smem[((pair * 2 + 1) * 64 + ra) * 68 + cf * 16 + ln15]);
              float g3b = b2f(smem[((pair * 2 + 1) * 64 + rb) * 68 + cf * 16 + ln15]);
              float i_ = sigm(acc[t][0][cf][2 * kp] + acc[t][0][cf][2 * kp + 1] + xwop[col]);
              float o_ = sigm(acc[t][1][cf][2 * kp] + acc[t][1][cf][2 * kp + 1] + xwop[1024 + col]);
              float u_ = tanhf_(g2a + g2b + xwop[2048 + col]);
              float f0 = sigm(g3a + xwop[3072 + col]);
              float f1 = sigm(g3b + xwop[3072 + col]);
              float c = i_ * u_ + f0 * c_in[(size_t)(2 * np) * 1024 + col]
                                + f1 * c_in[(size_t)(2 * np + 1) * 1024 + col];
              float h = o_ * tanhf_(c);
              if (m_parents == 1) {
                out_root[col] = c;
                out_root[1024 + col] = h;
              } else {
                c_out[(size_t)np * 1024 + col] = c;
                h_out[(size_t)np * 1024 + col] = f2bf(h);
              }
            }
          }
      }
    }
  }
}

// ---------------------------------------------------------------------------
extern "C" void kernel_launch(void* const* d_in, const int* in_sizes, int n_in,
                              void* d_out, int out_size, void* d_ws, size_t ws_size,
                              hipStream_t stream) {
  const float* tokens = (const float*)d_in[0];
  const int* leaf_ids = (const int*)d_in[1];
  const int* op_ids = (const int*)d_in[2];
  const float* W0 = (const float*)d_in[3];
  const float* W1 = (const float*)d_in[4];
  const float* W2 = (const float*)d_in[5];
  const float* W3 = (const float*)d_in[6];
  const float* U0 = (const float*)d_in[7];
  const float* U1 = (const float*)d_in[8];
  const float* U2 = (const float*)d_in[9];
  const float* U3 = (const float*)d_in[10];
  const float* B0 = (const float*)d_in[11];
  const float* B1 = (const float*)d_in[12];
  const float* B2 = (const float*)d_in[13];
  const float* B3 = (const float*)d_in[14];
  const float* op_emb = (const float*)d_in[15];
  const float* c_init = (const float*)d_in[16];
  const float* h_init = (const float*)d_in[17];
  float* out = (float*)d_out;

  char* ws = (char*)d_ws;
  u16* Wb = (u16*)ws;                                  // frag-major W, 8 MB
  u16* Ub = Wb + (size_t)4 * 1024 * 1024;              // frag-major U, 8 MB
  u16* Xl = Ub + (size_t)4 * 1024 * 1024;
  u16* hA = Xl + (size_t)8192 * 1024;
  u16* hB = hA + (size_t)8192 * 1024;
  float* cA = (float*)(hB + (size_t)4096 * 1024);
  float* cB = cA + (size_t)8192 * 1024;
  float* xw = cB + (size_t)4096 * 1024;
  float* lc = xw + 16 * 1024;

  convert_frag_kernel<<<4096, 256, 0, stream>>>(W0, W1, W2, W3, U0, U1, U2, U3, Wb, Ub);
  gather_leaf_kernel<<<8192, 256, 0, stream>>>(tokens, leaf_ids, Xl);
  precompute_kernel<<<84, 256, 0, stream>>>(op_emb, W0, W1, W2, W3, U0, U1, U2, U3,
                                            B0, B1, B2, B3, h_init, xw, lc);

  // leaves: 8192 rows -> 64 rowgroups x 16 stripes
  tree_gemm<<<64 * 16, 256, 0, stream>>>(Xl, Wb, lc, nullptr, c_init,
                                         cA, hA, 8192, 0, 1, out);

  const u16* hin = hA; const float* cin = cA;
  u16* hout = hB; float* cout = cB;
  for (int l = 12; l >= 0; --l) {
    int m = 1 << l;
    int nrows = 2 * m;
    int rg = (nrows + 127) / 128;
    tree_gemm<<<rg * 16, 256, 0, stream>>>(hin, Ub, xw, op_ids + (m - 1), cin,
                                           cout, hout, nrows, m, 0, out);
    const u16* th = hin; hin = hout; hout = (u16*)th;
    const float* tc = cin; cin = cout; cout = (float*)tc;
  }
}